// Round 13
// baseline (3474.316 us; speedup 1.0000x reference)
//
#include <hip/hip_runtime.h>

// GRU recurrence (round 13 = round 12 with the volatile-load compile fix).
// r11: gi-precompute + LDS w_state -> 1076us, but VGPR stayed 128: "+v" pins
// let the compiler REMATERIALIZE w_hh loads each step -> w_hh still streams.
// This round: volatile loads (as 2x volatile u64 — uint4 can't bind volatile)
// for resident w_hh + "+a" AGPR pins under launch_bounds(512,1); git loads
// double-buffered one step ahead (issued during phase 2).
// Falsification gate: WRITE_SIZE > 300MB => spilled => LDS-resident w_hh next.

typedef __attribute__((ext_vector_type(8))) short short8;   // 8 x bf16 MFMA frag
typedef __attribute__((ext_vector_type(4))) float f32x4;

constexpr int B_ = 1024, T_ = 128, I_ = 128, H_ = 256, OUT_ = 64;
constexpr int ROWS = 16;
constexpr int NBLK = B_ / ROWS;  // 64

#define DEVI __device__ __forceinline__

DEVI unsigned short f2b(float f) {
    unsigned u = __builtin_bit_cast(unsigned, f);
    u += 0x7fffu + ((u >> 16) & 1u);
    return (unsigned short)(u >> 16);
}
DEVI float b2f(unsigned short s) {
    unsigned u = ((unsigned)s) << 16;
    return __builtin_bit_cast(float, u);
}
DEVI float sigmoidf_(float x) { float e = __expf(-x); return __fdividef(1.f, 1.f + e); }
DEVI float tanhf_(float x) { float e = __expf(2.f * x); return __fdividef(e - 1.f, e + 1.f); }

DEVI f32x4 ld4(const void* p) { return *reinterpret_cast<const f32x4*>(p); }
DEVI short8 ldg8(const unsigned short* p) {
    return __builtin_bit_cast(short8, *reinterpret_cast<const uint4*>(p));
}
DEVI short8 ldv8(const unsigned short* p) {   // volatile: cannot be remat'd
    const volatile unsigned long long* vp =
        reinterpret_cast<const volatile unsigned long long*>(p);
    unsigned long long lo = vp[0];
    unsigned long long hi = vp[1];
    union { unsigned long long u[2]; short8 v; } r;
    r.u[0] = lo; r.u[1] = hi;
    return r.v;
}
DEVI short8 pack8(f32x4 lo, f32x4 hi) {
    union { unsigned short s[8]; short8 v; } r;
#pragma unroll
    for (int e = 0; e < 4; ++e) { r.s[e] = f2b(lo[e]); r.s[4 + e] = f2b(hi[e]); }
    return r.v;
}
DEVI f32x4 mfma(short8 a, short8 b, f32x4 c) {
    return __builtin_amdgcn_mfma_f32_16x16x32_bf16(a, b, c, 0, 0, 0);
}
DEVI unsigned long long ldull(const unsigned short* p) {
    return *reinterpret_cast<const unsigned long long*>(p);
}
DEVI f32x4 ull2f4(unsigned long long raw) {
    f32x4 r;
#pragma unroll
    for (int e = 0; e < 4; ++e) r[e] = b2f((unsigned short)(raw >> (16 * e)));
    return r;
}

// XOR-swizzled [*][256] bf16 tile: byte ^= (row&7)<<4
DEVI unsigned short* swz(unsigned short* base, int row, int col) {
    int byte = (row * H_ + col) * 2;
    byte ^= (row & 7) << 4;
    return (unsigned short*)((char*)base + byte);
}
DEVI const unsigned short* swzc(const unsigned short* base, int row, int col) {
    int byte = (row * H_ + col) * 2;
    byte ^= (row & 7) << 4;
    return (const unsigned short*)((const char*)base + byte);
}

#define PIN8A(A) asm volatile("" : "+a"((A)[0]),"+a"((A)[1]),"+a"((A)[2]),\
    "+a"((A)[3]),"+a"((A)[4]),"+a"((A)[5]),"+a"((A)[6]),"+a"((A)[7]))
#define PIN6U(A) asm volatile("" : "+v"((A)[0]),"+v"((A)[1]),"+v"((A)[2]),\
    "+v"((A)[3]),"+v"((A)[4]),"+v"((A)[5]))

// ---- weight pre-conversion: f32 -> bf16 ----
__global__ void cvt_w(const float* __restrict__ src, unsigned short* __restrict__ dst, int n) {
    int i = (blockIdx.x * blockDim.x + threadIdx.x) * 8;
    if (i >= n) return;
    f32x4 lo = ld4(src + i), hi = ld4(src + i + 4);
    union { unsigned short s[8]; uint4 v; } r;
#pragma unroll
    for (int e = 0; e < 4; ++e) { r.s[e] = f2b(lo[e]); r.s[4 + e] = f2b(hi[e]); }
    *reinterpret_cast<uint4*>(dst + i) = r.v;
}

// ---- gi precompute: git[t][gr][b] = sum_k x[b,t,k] * w_ih[gr,k]  (bf16) ----
__global__ __launch_bounds__(256) void gi_gemm(
    const float* __restrict__ a, const unsigned short* __restrict__ wih,
    unsigned short* __restrict__ git)
{
    const int tid = threadIdx.x;
    const int ww = tid >> 6;
    const int l = tid & 63;
    const int m = l & 15, kg = l >> 4;
    const int gr0 = blockIdx.x * 16;
    const int t = blockIdx.y;

    short8 aw[4];
#pragma unroll
    for (int kt = 0; kt < 4; ++kt)
        aw[kt] = ldg8(wih + (size_t)(gr0 + m) * I_ + kt * 32 + kg * 8);

#pragma unroll 4
    for (int bt = 0; bt < 16; ++bt) {
        const int b0 = ww * 256 + bt * 16;
        const float* xr = a + (size_t)(b0 + m) * T_ * I_ + (size_t)t * I_ + kg * 8;
        short8 xb[4];
#pragma unroll
        for (int kt = 0; kt < 4; ++kt)
            xb[kt] = pack8(ld4(xr + kt * 32), ld4(xr + kt * 32 + 4));
        f32x4 acc = {0.f, 0.f, 0.f, 0.f};
#pragma unroll
        for (int kt = 0; kt < 4; ++kt) acc = mfma(aw[kt], xb[kt], acc);
#pragma unroll
        for (int v = 0; v < 4; ++v)
            git[((size_t)t * 768 + gr0 + kg * 4 + v) * B_ + b0 + m] = f2b(acc[v]);
    }
}

template <bool PREGI>
__global__ __launch_bounds__(512, 1) void gru_fused(
    const float* __restrict__ s0,             // [B][H] f32
    const float* __restrict__ a,              // [B][T][I] f32 (fallback only)
    const unsigned short* __restrict__ git,   // [T][768][B] bf16 (PREGI)
    const unsigned short* __restrict__ w_ih,  // [3H][I] bf16 (fallback only)
    const unsigned short* __restrict__ w_hh,  // [3H][H] bf16
    const unsigned short* __restrict__ w_rw,  // [OUT][H] bf16
    const unsigned short* __restrict__ w_st,  // [H][H] bf16
    float* __restrict__ out_r,                // [T][OUT] f32
    float* __restrict__ out_s)                // [B][T][H] f32
{
    __shared__ unsigned short wst_l[H_ * H_];   // 131072 B, swizzled
    __shared__ unsigned short h16[ROWS * H_];   // 8192 B
    __shared__ unsigned short hn16[ROWS * H_];  // 8192 B

    const int tid = threadIdx.x;
    const int w = tid >> 6;
    const int l = tid & 63;
    const int m = l & 15;
    const int kg = l >> 4;
    const int R0 = blockIdx.x * ROWS;
    const int g0 = (2 * w + 0) * 16 + m;
    const int g1 = (2 * w + 1) * 16 + m;

    // stage w_state into LDS, swizzled
#pragma unroll
    for (int i = 0; i < 16; ++i) {
        const int idx = (tid + i * 512) * 8;
        *reinterpret_cast<uint4*>(swz(wst_l, idx >> 8, idx & 255)) =
            *reinterpret_cast<const uint4*>(w_st + idx);
    }
    // init h16
    {
        const int pr = tid >> 5, pc = (tid & 31) * 8;
        const float* sp = &s0[(size_t)(R0 + pr) * H_ + pc];
        *reinterpret_cast<uint4*>(swz(h16, pr, pc)) =
            __builtin_bit_cast(uint4, pack8(ld4(sp), ld4(sp + 4)));
    }
    float hreg0[4], hreg1[4];
#pragma unroll
    for (int v = 0; v < 4; ++v) {
        hreg0[v] = s0[(size_t)(R0 + kg * 4 + v) * H_ + g0];
        hreg1[v] = s0[(size_t)(R0 + kg * 4 + v) * H_ + g1];
    }

    // REGISTER-RESIDENT w_hh: volatile loads (no remat) + AGPR pins.
    // 48 fragments = 192 regs/lane in the AGPR half of the unified file.
    short8 whR[16], whZ[16], whN[16];   // [u*8+kt]
#pragma unroll
    for (int u = 0; u < 2; ++u) {
        const int g = (u == 0) ? g0 : g1;
#pragma unroll
        for (int kt = 0; kt < 8; ++kt) {
            whR[u * 8 + kt] = ldv8(w_hh + (size_t)(g)       * H_ + kt * 32 + kg * 8);
            whZ[u * 8 + kt] = ldv8(w_hh + (size_t)(g + 256) * H_ + kt * 32 + kg * 8);
            whN[u * 8 + kt] = ldv8(w_hh + (size_t)(g + 512) * H_ + kt * 32 + kg * 8);
        }
    }
    PIN8A(whR); PIN8A(whR + 8);
    PIN8A(whZ); PIN8A(whZ + 8);
    PIN8A(whN); PIN8A(whN + 8);
    __syncthreads();

    // git double-buffer: raw u64 per gate-slice (6 per step), loaded 1 ahead
    unsigned long long gr_[6];
    if constexpr (PREGI) {
        const unsigned short* gt = git + R0 + kg * 4;   // t = 0
        gr_[0] = ldull(gt + (size_t)(g0)       * B_);
        gr_[1] = ldull(gt + (size_t)(g0 + 256) * B_);
        gr_[2] = ldull(gt + (size_t)(g0 + 512) * B_);
        gr_[3] = ldull(gt + (size_t)(g1)       * B_);
        gr_[4] = ldull(gt + (size_t)(g1 + 256) * B_);
        gr_[5] = ldull(gt + (size_t)(g1 + 512) * B_);
    }

    for (int t = 0; t < T_; ++t) {
        // keep residents live (loop-carried AGPR dep; volatile src -> no remat)
        PIN8A(whR); PIN8A(whR + 8);
        PIN8A(whZ); PIN8A(whZ + 8);
        PIN8A(whN); PIN8A(whN + 8);

        f32x4 ar0, az0, ani0, ar1, az1, ani1;
        if constexpr (PREGI) {
            PIN6U(gr_);
            ar0 = ull2f4(gr_[0]); az0 = ull2f4(gr_[1]); ani0 = ull2f4(gr_[2]);
            ar1 = ull2f4(gr_[3]); az1 = ull2f4(gr_[4]); ani1 = ull2f4(gr_[5]);
        } else {
            ar0 = az0 = ani0 = ar1 = az1 = ani1 = f32x4{0.f, 0.f, 0.f, 0.f};
        }

        short8 ha[8];
#pragma unroll
        for (int kt = 0; kt < 8; ++kt)
            ha[kt] = ldg8(swzc(h16, m, kt * 32 + kg * 8));

        if constexpr (!PREGI) {  // fallback: x-part inline (streams w_ih)
            short8 xa[4];
            const float* xr = a + ((size_t)(R0 + m) * T_ + t) * I_ + kg * 8;
#pragma unroll
            for (int kt = 0; kt < 4; ++kt)
                xa[kt] = pack8(ld4(xr + kt * 32), ld4(xr + kt * 32 + 4));
            const unsigned short* p0 = w_ih + (size_t)g0 * I_ + kg * 8;
            const unsigned short* p1 = w_ih + (size_t)g1 * I_ + kg * 8;
#pragma unroll
            for (int kt = 0; kt < 4; ++kt) {
                ar0  = mfma(xa[kt], ldg8(p0 + kt * 32),            ar0);
                az0  = mfma(xa[kt], ldg8(p0 + 256 * I_ + kt * 32), az0);
                ani0 = mfma(xa[kt], ldg8(p0 + 512 * I_ + kt * 32), ani0);
                ar1  = mfma(xa[kt], ldg8(p1 + kt * 32),            ar1);
                az1  = mfma(xa[kt], ldg8(p1 + 256 * I_ + kt * 32), az1);
                ani1 = mfma(xa[kt], ldg8(p1 + 512 * I_ + kt * 32), ani1);
            }
        }

        // ---- h-part: ALL weights register-resident ----
        f32x4 anh0 = {0,0,0,0}, anh1 = {0,0,0,0};
#pragma unroll
        for (int kt = 0; kt < 8; ++kt) {
            ar0  = mfma(ha[kt], whR[kt],     ar0);
            az0  = mfma(ha[kt], whZ[kt],     az0);
            anh0 = mfma(ha[kt], whN[kt],     anh0);
            ar1  = mfma(ha[kt], whR[8 + kt], ar1);
            az1  = mfma(ha[kt], whZ[8 + kt], az1);
            anh1 = mfma(ha[kt], whN[8 + kt], anh1);
        }
        // ---- gates -> h_new ----
#pragma unroll
        for (int v = 0; v < 4; ++v) {
            const int row = kg * 4 + v;
            {
                const float rg = sigmoidf_(ar0[v]);
                const float zg = sigmoidf_(az0[v]);
                const float ng = tanhf_(ani0[v] + rg * anh0[v]);
                *swz(hn16, row, g0) = f2b((1.f - zg) * ng + zg * hreg0[v]);
            }
            {
                const float rg = sigmoidf_(ar1[v]);
                const float zg = sigmoidf_(az1[v]);
                const float ng = tanhf_(ani1[v] + rg * anh1[v]);
                *swz(hn16, row, g1) = f2b((1.f - zg) * ng + zg * hreg1[v]);
            }
        }
        __syncthreads();

        // ---- issue git(t+1) loads: a full phase ahead of their use ----
        if constexpr (PREGI) {
            const int tn = (t + 1 < T_) ? t + 1 : t;
            const unsigned short* gt = git + (size_t)tn * 768 * B_ + R0 + kg * 4;
            gr_[0] = ldull(gt + (size_t)(g0)       * B_);
            gr_[1] = ldull(gt + (size_t)(g0 + 256) * B_);
            gr_[2] = ldull(gt + (size_t)(g0 + 512) * B_);
            gr_[3] = ldull(gt + (size_t)(g1)       * B_);
            gr_[4] = ldull(gt + (size_t)(g1 + 256) * B_);
            gr_[5] = ldull(gt + (size_t)(g1 + 512) * B_);
            PIN6U(gr_);
        }

        // ---- phase 2: all operands LDS/register-resident ----
        short8 na[8];
#pragma unroll
        for (int kt = 0; kt < 8; ++kt)
            na[kt] = ldg8(swzc(hn16, m, kt * 32 + kg * 8));
        f32x4 sa0 = {0,0,0,0}, sa1 = {0,0,0,0};
#pragma unroll
        for (int kt = 0; kt < 8; ++kt) {
            sa0 = mfma(na[kt], ldg8(swzc(wst_l, g0, kt * 32 + kg * 8)), sa0);
            sa1 = mfma(na[kt], ldg8(swzc(wst_l, g1, kt * 32 + kg * 8)), sa1);
        }
#pragma unroll
        for (int v = 0; v < 4; ++v) {
            const int row = kg * 4 + v;
            const float u0 = sigmoidf_(sa0[v]);
            const float u1 = sigmoidf_(sa1[v]);
            hreg0[v] = u0; hreg1[v] = u1;
            *swz(h16, row, g0) = f2b(u0);
            *swz(h16, row, g1) = f2b(u1);
            float* dst = &out_s[((size_t)(R0 + row) * T_ + t) * H_];
            dst[g0] = u0;
            dst[g1] = u1;
        }
        if (blockIdx.x == 0 && w < 4) {  // r_t
            const int o = w * 16 + m;
            f32x4 accr = {0,0,0,0};
            const unsigned short* p = w_rw + (size_t)o * H_ + kg * 8;
#pragma unroll
            for (int kt = 0; kt < 8; ++kt)
                accr = mfma(na[kt], ldg8(p + kt * 32), accr);
            if (kg == 0)
                out_r[t * OUT_ + o] = sigmoidf_(accr[0]);
        }
        __syncthreads();
    }
}

extern "C" void kernel_launch(void* const* d_in, const int* in_sizes, int n_in,
                              void* d_out, int out_size, void* d_ws, size_t ws_size,
                              hipStream_t stream) {
    const float* s0  = (const float*)d_in[0];
    const float* a   = (const float*)d_in[1];
    const float* wih = (const float*)d_in[2];
    const float* whh = (const float*)d_in[3];
    const float* wrw = (const float*)d_in[4];
    const float* wst = (const float*)d_in[5];

    const size_t git_elems = (size_t)T_ * 768 * B_;        // 100,663,296 bf16
    const size_t wtot = 98304 + 196608 + 16384 + 65536;    // 376,832 bf16
    const bool pregi = ws_size >= (git_elems + wtot) * 2;

    unsigned short* ws16 = (unsigned short*)d_ws;
    unsigned short* git  = pregi ? ws16 : nullptr;
    unsigned short* wih16 = ws16 + (pregi ? git_elems : 0);
    unsigned short* whh16 = wih16 + 98304;
    unsigned short* wrw16 = whh16 + 196608;
    unsigned short* wst16 = wrw16 + 16384;

    cvt_w<<<98304  / (256 * 8), 256, 0, stream>>>(wih, wih16, 98304);
    cvt_w<<<196608 / (256 * 8), 256, 0, stream>>>(whh, whh16, 196608);
    cvt_w<<<16384  / (256 * 8), 256, 0, stream>>>(wrw, wrw16, 16384);
    cvt_w<<<65536  / (256 * 8), 256, 0, stream>>>(wst, wst16, 65536);

    float* out = (float*)d_out;
    if (pregi) {
        gi_gemm<<<dim3(48, T_), 256, 0, stream>>>(a, wih16, git);
        gru_fused<true><<<NBLK, 512, 0, stream>>>(s0, a, git, wih16, whh16,
                                                  wrw16, wst16,
                                                  out, out + (size_t)T_ * OUT_);
    } else {
        gru_fused<false><<<NBLK, 512, 0, stream>>>(s0, a, nullptr, wih16, whh16,
                                                   wrw16, wst16,
                                                   out, out + (size_t)T_ * OUT_);
    }
}

// Round 14
// 2305.347 us; speedup vs baseline: 1.5071x; 1.5071x over previous
//
#include <hip/hip_runtime.h>

// GRU recurrence (round 14).
// r13: "+a" AGPR residency => scratch spill (WRITE 1.9GB). Register residency
// for w_hh is dead (remat / spill in all 3 variants). Revert to r11 structure
// (1076us) and fix its measured profile:
//  (1) git re-layout [t][block][gate][16]: contiguous 24.6KB/block/step
//      -> FETCH halves, coalesced; double-buffered one step ahead (from r13).
//  (2) nontemporal git loads + out_s stores: stop evicting w_hh from L2.
//  (3) w_hh streamed with r6-proven ping-pong pinned 8-frag batches.
//  (4) gi_gemm: swapped mfma operands -> packed 8B nt stores.

typedef __attribute__((ext_vector_type(8))) short short8;   // 8 x bf16 MFMA frag
typedef __attribute__((ext_vector_type(4))) float f32x4;

constexpr int B_ = 1024, T_ = 128, I_ = 128, H_ = 256, OUT_ = 64;
constexpr int ROWS = 16;
constexpr int NBLK = B_ / ROWS;  // 64

#define DEVI __device__ __forceinline__

DEVI unsigned short f2b(float f) {
    unsigned u = __builtin_bit_cast(unsigned, f);
    u += 0x7fffu + ((u >> 16) & 1u);
    return (unsigned short)(u >> 16);
}
DEVI float b2f(unsigned short s) {
    unsigned u = ((unsigned)s) << 16;
    return __builtin_bit_cast(float, u);
}
DEVI float sigmoidf_(float x) { float e = __expf(-x); return __fdividef(1.f, 1.f + e); }
DEVI float tanhf_(float x) { float e = __expf(2.f * x); return __fdividef(e - 1.f, e + 1.f); }

DEVI f32x4 ld4(const void* p) { return *reinterpret_cast<const f32x4*>(p); }
DEVI short8 ldg8(const unsigned short* p) {
    return __builtin_bit_cast(short8, *reinterpret_cast<const uint4*>(p));
}
DEVI short8 pack8(f32x4 lo, f32x4 hi) {
    union { unsigned short s[8]; short8 v; } r;
#pragma unroll
    for (int e = 0; e < 4; ++e) { r.s[e] = f2b(lo[e]); r.s[4 + e] = f2b(hi[e]); }
    return r.v;
}
DEVI f32x4 mfma(short8 a, short8 b, f32x4 c) {
    return __builtin_amdgcn_mfma_f32_16x16x32_bf16(a, b, c, 0, 0, 0);
}
DEVI f32x4 ull2f4(unsigned long long raw) {
    f32x4 r;
#pragma unroll
    for (int e = 0; e < 4; ++e) r[e] = b2f((unsigned short)(raw >> (16 * e)));
    return r;
}

// XOR-swizzled [*][256] bf16 tile: byte ^= (row&7)<<4
DEVI unsigned short* swz(unsigned short* base, int row, int col) {
    int byte = (row * H_ + col) * 2;
    byte ^= (row & 7) << 4;
    return (unsigned short*)((char*)base + byte);
}
DEVI const unsigned short* swzc(const unsigned short* base, int row, int col) {
    int byte = (row * H_ + col) * 2;
    byte ^= (row & 7) << 4;
    return (const unsigned short*)((const char*)base + byte);
}

#define PIN8(A) asm volatile("" : "+v"((A)[0]),"+v"((A)[1]),"+v"((A)[2]),\
    "+v"((A)[3]),"+v"((A)[4]),"+v"((A)[5]),"+v"((A)[6]),"+v"((A)[7]))

// ---- weight pre-conversion: f32 -> bf16 ----
__global__ void cvt_w(const float* __restrict__ src, unsigned short* __restrict__ dst, int n) {
    int i = (blockIdx.x * blockDim.x + threadIdx.x) * 8;
    if (i >= n) return;
    f32x4 lo = ld4(src + i), hi = ld4(src + i + 4);
    union { unsigned short s[8]; uint4 v; } r;
#pragma unroll
    for (int e = 0; e < 4; ++e) { r.s[e] = f2b(lo[e]); r.s[4 + e] = f2b(hi[e]); }
    *reinterpret_cast<uint4*>(dst + i) = r.v;
}

// ---- gi precompute into layout git[((t*64 + blk)*768 + gate)*16 + bi] ----
// Swapped operands: mfma(xb, aw) -> lane holds D[b = kg*4+v][gate = gr0+m]
// -> 4 consecutive bi per lane -> one packed 8B nt store.
__global__ __launch_bounds__(256) void gi_gemm(
    const float* __restrict__ a, const unsigned short* __restrict__ wih,
    unsigned short* __restrict__ git)
{
    const int tid = threadIdx.x;
    const int ww = tid >> 6;
    const int l = tid & 63;
    const int m = l & 15, kg = l >> 4;
    const int gr0 = blockIdx.x * 16;
    const int t = blockIdx.y;

    short8 aw[4];
#pragma unroll
    for (int kt = 0; kt < 4; ++kt)
        aw[kt] = ldg8(wih + (size_t)(gr0 + m) * I_ + kt * 32 + kg * 8);

#pragma unroll 4
    for (int bt = 0; bt < 16; ++bt) {
        const int b0 = ww * 256 + bt * 16;
        const int blk = (b0 >> 4);   // b0/16
        const float* xr = a + (size_t)(b0 + m) * T_ * I_ + (size_t)t * I_ + kg * 8;
        short8 xb[4];
#pragma unroll
        for (int kt = 0; kt < 4; ++kt)
            xb[kt] = pack8(ld4(xr + kt * 32), ld4(xr + kt * 32 + 4));
        f32x4 acc = {0.f, 0.f, 0.f, 0.f};
#pragma unroll
        for (int kt = 0; kt < 4; ++kt) acc = mfma(xb[kt], aw[kt], acc);
        // lane (m,kg): D[b=kg*4+v][gate=gr0+m] -> pack 4 bf16, 8B nt store
        unsigned long long pk = 0;
#pragma unroll
        for (int v = 0; v < 4; ++v)
            pk |= (unsigned long long)f2b(acc[v]) << (16 * v);
        unsigned long long* dst = reinterpret_cast<unsigned long long*>(
            git + (((size_t)t * 64 + blk) * 768 + gr0 + m) * 16 + kg * 4);
        __builtin_nontemporal_store(pk, dst);
    }
}

template <bool PREGI>
__global__ __launch_bounds__(512, 1) void gru_fused(
    const float* __restrict__ s0,             // [B][H] f32
    const float* __restrict__ a,              // [B][T][I] f32 (fallback only)
    const unsigned short* __restrict__ git,   // [T][64][768][16] bf16 (PREGI)
    const unsigned short* __restrict__ w_ih,  // [3H][I] bf16 (fallback only)
    const unsigned short* __restrict__ w_hh,  // [3H][H] bf16
    const unsigned short* __restrict__ w_rw,  // [OUT][H] bf16
    const unsigned short* __restrict__ w_st,  // [H][H] bf16
    float* __restrict__ out_r,                // [T][OUT] f32
    float* __restrict__ out_s)                // [B][T][H] f32
{
    __shared__ unsigned short wst_l[H_ * H_];   // 131072 B, swizzled
    __shared__ unsigned short h16[ROWS * H_];   // 8192 B
    __shared__ unsigned short hn16[ROWS * H_];  // 8192 B

    const int tid = threadIdx.x;
    const int w = tid >> 6;
    const int l = tid & 63;
    const int m = l & 15;
    const int kg = l >> 4;
    const int R0 = blockIdx.x * ROWS;
    const int g0 = (2 * w + 0) * 16 + m;
    const int g1 = (2 * w + 1) * 16 + m;

    // stage w_state into LDS, swizzled
#pragma unroll
    for (int i = 0; i < 16; ++i) {
        const int idx = (tid + i * 512) * 8;
        *reinterpret_cast<uint4*>(swz(wst_l, idx >> 8, idx & 255)) =
            *reinterpret_cast<const uint4*>(w_st + idx);
    }
    // init h16
    {
        const int pr = tid >> 5, pc = (tid & 31) * 8;
        const float* sp = &s0[(size_t)(R0 + pr) * H_ + pc];
        *reinterpret_cast<uint4*>(swz(h16, pr, pc)) =
            __builtin_bit_cast(uint4, pack8(ld4(sp), ld4(sp + 4)));
    }
    float hreg0[4], hreg1[4];
#pragma unroll
    for (int v = 0; v < 4; ++v) {
        hreg0[v] = s0[(size_t)(R0 + kg * 4 + v) * H_ + g0];
        hreg1[v] = s0[(size_t)(R0 + kg * 4 + v) * H_ + g1];
    }
    __syncthreads();

    const unsigned short* pwh0 = w_hh + (size_t)g0 * H_ + kg * 8;
    const unsigned short* pwh1 = w_hh + (size_t)g1 * H_ + kg * 8;

    // git double-buffer: 6 raw u64 per step, loaded one step ahead (nt)
    unsigned long long gr_[6];
    if constexpr (PREGI) {
        const unsigned short* gt = git + (size_t)blockIdx.x * 768 * 16;  // t=0
#pragma unroll
        for (int i = 0; i < 3; ++i) {
            gr_[i]     = __builtin_nontemporal_load(
                reinterpret_cast<const unsigned long long*>(gt + (g0 + i * 256) * 16 + kg * 4));
            gr_[3 + i] = __builtin_nontemporal_load(
                reinterpret_cast<const unsigned long long*>(gt + (g1 + i * 256) * 16 + kg * 4));
        }
    }

    for (int t = 0; t < T_; ++t) {
        // ---- consume git(t), then immediately issue git(t+1) nt loads ----
        f32x4 ar0, az0, ani0, ar1, az1, ani1;
        if constexpr (PREGI) {
            ar0 = ull2f4(gr_[0]); az0 = ull2f4(gr_[1]); ani0 = ull2f4(gr_[2]);
            ar1 = ull2f4(gr_[3]); az1 = ull2f4(gr_[4]); ani1 = ull2f4(gr_[5]);
            const int tn = (t + 1 < T_) ? t + 1 : t;
            const unsigned short* gt =
                git + ((size_t)tn * 64 + blockIdx.x) * 768 * 16;
#pragma unroll
            for (int i = 0; i < 3; ++i) {
                gr_[i]     = __builtin_nontemporal_load(
                    reinterpret_cast<const unsigned long long*>(gt + (g0 + i * 256) * 16 + kg * 4));
                gr_[3 + i] = __builtin_nontemporal_load(
                    reinterpret_cast<const unsigned long long*>(gt + (g1 + i * 256) * 16 + kg * 4));
            }
        } else {
            ar0 = az0 = ani0 = ar1 = az1 = ani1 = f32x4{0.f, 0.f, 0.f, 0.f};
        }

        short8 ha[8];
#pragma unroll
        for (int kt = 0; kt < 8; ++kt)
            ha[kt] = ldg8(swzc(h16, m, kt * 32 + kg * 8));

        if constexpr (!PREGI) {  // fallback: x-part inline (streams w_ih)
            short8 xa[4];
            const float* xr = a + ((size_t)(R0 + m) * T_ + t) * I_ + kg * 8;
#pragma unroll
            for (int kt = 0; kt < 4; ++kt)
                xa[kt] = pack8(ld4(xr + kt * 32), ld4(xr + kt * 32 + 4));
            const unsigned short* p0 = w_ih + (size_t)g0 * I_ + kg * 8;
            const unsigned short* p1 = w_ih + (size_t)g1 * I_ + kg * 8;
#pragma unroll
            for (int kt = 0; kt < 4; ++kt) {
                ar0  = mfma(xa[kt], ldg8(p0 + kt * 32),            ar0);
                az0  = mfma(xa[kt], ldg8(p0 + 256 * I_ + kt * 32), az0);
                ani0 = mfma(xa[kt], ldg8(p0 + 512 * I_ + kt * 32), ani0);
                ar1  = mfma(xa[kt], ldg8(p1 + kt * 32),            ar1);
                az1  = mfma(xa[kt], ldg8(p1 + 256 * I_ + kt * 32), az1);
                ani1 = mfma(xa[kt], ldg8(p1 + 512 * I_ + kt * 32), ani1);
            }
        }

        // ---- h-part: w_hh streamed, r6-proven ping-pong pinned batches ----
        f32x4 anh0 = {0,0,0,0}, anh1 = {0,0,0,0};
        {
            short8 bA[8], bB[8];
#pragma unroll
            for (int kt = 0; kt < 8; ++kt) bA[kt] = ldg8(pwh0 + kt * 32);            // r g0
#pragma unroll
            for (int kt = 0; kt < 8; ++kt) bB[kt] = ldg8(pwh1 + kt * 32);            // r g1
            PIN8(bA);
#pragma unroll
            for (int kt = 0; kt < 8; ++kt) ar0 = mfma(ha[kt], bA[kt], ar0);
#pragma unroll
            for (int kt = 0; kt < 8; ++kt) bA[kt] = ldg8(pwh0 + 256 * H_ + kt * 32); // z g0
            PIN8(bB);
#pragma unroll
            for (int kt = 0; kt < 8; ++kt) ar1 = mfma(ha[kt], bB[kt], ar1);
#pragma unroll
            for (int kt = 0; kt < 8; ++kt) bB[kt] = ldg8(pwh1 + 256 * H_ + kt * 32); // z g1
            PIN8(bA);
#pragma unroll
            for (int kt = 0; kt < 8; ++kt) az0 = mfma(ha[kt], bA[kt], az0);
#pragma unroll
            for (int kt = 0; kt < 8; ++kt) bA[kt] = ldg8(pwh0 + 512 * H_ + kt * 32); // n g0
            PIN8(bB);
#pragma unroll
            for (int kt = 0; kt < 8; ++kt) az1 = mfma(ha[kt], bB[kt], az1);
#pragma unroll
            for (int kt = 0; kt < 8; ++kt) bB[kt] = ldg8(pwh1 + 512 * H_ + kt * 32); // n g1
            PIN8(bA);
#pragma unroll
            for (int kt = 0; kt < 8; ++kt) anh0 = mfma(ha[kt], bA[kt], anh0);
            PIN8(bB);
#pragma unroll
            for (int kt = 0; kt < 8; ++kt) anh1 = mfma(ha[kt], bB[kt], anh1);
        }

        // ---- gates -> h_new ----
#pragma unroll
        for (int v = 0; v < 4; ++v) {
            const int row = kg * 4 + v;
            {
                const float rg = sigmoidf_(ar0[v]);
                const float zg = sigmoidf_(az0[v]);
                const float ng = tanhf_(ani0[v] + rg * anh0[v]);
                *swz(hn16, row, g0) = f2b((1.f - zg) * ng + zg * hreg0[v]);
            }
            {
                const float rg = sigmoidf_(ar1[v]);
                const float zg = sigmoidf_(az1[v]);
                const float ng = tanhf_(ani1[v] + rg * anh1[v]);
                *swz(hn16, row, g1) = f2b((1.f - zg) * ng + zg * hreg1[v]);
            }
        }
        __syncthreads();

        // ---- phase 2: all operands LDS-resident ----
        short8 na[8];
#pragma unroll
        for (int kt = 0; kt < 8; ++kt)
            na[kt] = ldg8(swzc(hn16, m, kt * 32 + kg * 8));
        f32x4 sa0 = {0,0,0,0}, sa1 = {0,0,0,0};
#pragma unroll
        for (int kt = 0; kt < 8; ++kt) {
            sa0 = mfma(na[kt], ldg8(swzc(wst_l, g0, kt * 32 + kg * 8)), sa0);
            sa1 = mfma(na[kt], ldg8(swzc(wst_l, g1, kt * 32 + kg * 8)), sa1);
        }
#pragma unroll
        for (int v = 0; v < 4; ++v) {
            const int row = kg * 4 + v;
            const float u0 = sigmoidf_(sa0[v]);
            const float u1 = sigmoidf_(sa1[v]);
            hreg0[v] = u0; hreg1[v] = u1;
            *swz(h16, row, g0) = f2b(u0);
            *swz(h16, row, g1) = f2b(u1);
            float* dst = &out_s[((size_t)(R0 + row) * T_ + t) * H_];
            __builtin_nontemporal_store(u0, dst + g0);
            __builtin_nontemporal_store(u1, dst + g1);
        }
        if (blockIdx.x == 0 && w < 4) {  // r_t
            const int o = w * 16 + m;
            f32x4 accr = {0,0,0,0};
            const unsigned short* p = w_rw + (size_t)o * H_ + kg * 8;
#pragma unroll
            for (int kt = 0; kt < 8; ++kt)
                accr = mfma(na[kt], ldg8(p + kt * 32), accr);
            if (kg == 0)
                out_r[t * OUT_ + o] = sigmoidf_(accr[0]);
        }
        __syncthreads();
    }
}

extern "C" void kernel_launch(void* const* d_in, const int* in_sizes, int n_in,
                              void* d_out, int out_size, void* d_ws, size_t ws_size,
                              hipStream_t stream) {
    const float* s0  = (const float*)d_in[0];
    const float* a   = (const float*)d_in[1];
    const float* wih = (const float*)d_in[2];
    const float* whh = (const float*)d_in[3];
    const float* wrw = (const float*)d_in[4];
    const float* wst = (const float*)d_in[5];

    const size_t git_elems = (size_t)T_ * 768 * B_;        // 100,663,296 bf16
    const size_t wtot = 98304 + 196608 + 16384 + 65536;    // 376,832 bf16
    const bool pregi = ws_size >= (git_elems + wtot) * 2;

    unsigned short* ws16 = (unsigned short*)d_ws;
    unsigned short* git  = pregi ? ws16 : nullptr;
    unsigned short* wih16 = ws16 + (pregi ? git_elems : 0);
    unsigned short* whh16 = wih16 + 98304;
    unsigned short* wrw16 = whh16 + 196608;
    unsigned short* wst16 = wrw16 + 16384;

    cvt_w<<<98304  / (256 * 8), 256, 0, stream>>>(wih, wih16, 98304);
    cvt_w<<<196608 / (256 * 8), 256, 0, stream>>>(whh, whh16, 196608);
    cvt_w<<<16384  / (256 * 8), 256, 0, stream>>>(wrw, wrw16, 16384);
    cvt_w<<<65536  / (256 * 8), 256, 0, stream>>>(wst, wst16, 65536);

    float* out = (float*)d_out;
    if (pregi) {
        gi_gemm<<<dim3(48, T_), 256, 0, stream>>>(a, wih16, git);
        gru_fused<true><<<NBLK, 512, 0, stream>>>(s0, a, git, wih16, whh16,
                                                  wrw16, wst16,
                                                  out, out + (size_t)T_ * OUT_);
    } else {
        gru_fused<false><<<NBLK, 512, 0, stream>>>(s0, a, nullptr, wih16, whh16,
                                                   wrw16, wst16,
                                                   out, out + (size_t)T_ * OUT_);
    }
}